// Round 1
// baseline (425.519 us; speedup 1.0000x reference)
//
#include <hip/hip_runtime.h>

// NeuralGraphOutput: out[b,o] = sum_a mask[b,a] * relu( sum_f x[b,a,f] * W[f,o] + bias[o] )
//   x[b,a,:] = concat(atoms[b,a,0:64], sum_d bonds[b,a,d,0:16])   (80 features)
//   mask[b,a] = any(edges[b,a,d] != -1)
// B=2048, A=256, D=8, FA=64, FB=16, FP=256

#define NB 2048
#define NA 256
#define ND 8
#define NFA 64
#define NFB 16
#define NF 80      // FA + FB
#define NFP 256
#define ATILE 4

__launch_bounds__(256, 4)
__global__ void ngf_fp32_kernel(const float* __restrict__ atoms,
                                const float* __restrict__ bonds,
                                const int*   __restrict__ edges,
                                const float* __restrict__ W,
                                const float* __restrict__ bias,
                                float* __restrict__ out)
{
    const int b    = blockIdx.x;     // molecule
    const int tid  = threadIdx.x;    // 0..255
    const int o    = tid;            // output column owned by this thread
    const int wave = tid >> 6;       // 0..3  (== atom slot within tile for staging)
    const int lane = tid & 63;

    // x tile, feature-major so 4 atoms' values for one f are one float4 (uniform broadcast read)
    __shared__ float4 xbuf4[NF];           // [f] -> x[f][atom0..3]
    __shared__ float  maskbuf[ATILE];
    float* xbuf = (float*)xbuf4;

    // W column in registers (block-uniform x broadcasts from LDS; per-thread W must be in regs)
    float w[NF];
    #pragma unroll
    for (int f = 0; f < NF; ++f) w[f] = W[f * NFP + o];
    const float bv = bias[o];

    float acc = 0.0f;
    const size_t molBase = (size_t)b * NA;   // atom row base for this molecule

    for (int abase = 0; abase < NA; abase += ATILE) {
        // ---------------- stage 4 atoms into LDS ----------------
        // atoms part: 4*64 = 256 floats, one per thread, coalesced
        {
            const int a_i = tid >> 6;        // atom slot
            const int f   = tid & 63;        // feature
            float v = atoms[(molBase + abase + a_i) * NFA + f];
            xbuf[f * ATILE + a_i] = v;
        }
        // bonds part: wave `wave` handles atom slot `wave`.
        // 128 floats per atom read as 64 float2 (coalesced 512B per wave),
        // lane = d*8 + fb2; reduce over d with shfl_xor(8,16,32).
        {
            const int a_i = wave;
            const float2* bp =
                (const float2*)(bonds + (molBase + abase + a_i) * (ND * NFB));
            float2 v = bp[lane];
            #pragma unroll
            for (int m = 8; m < 64; m <<= 1) {
                v.x += __shfl_xor(v.x, m, 64);
                v.y += __shfl_xor(v.y, m, 64);
            }
            if (lane < 8) {   // lane == fb2 for d==0 holds the full sum
                xbuf[(NFA + 2 * lane    ) * ATILE + a_i] = v.x;
                xbuf[(NFA + 2 * lane + 1) * ATILE + a_i] = v.y;
            }
        }
        // degree mask: any(edges != -1) over the 8 neighbor slots
        {
            const int a_i = wave;
            int e = (lane < ND) ? edges[(molBase + abase + a_i) * ND + lane] : -1;
            unsigned long long bal = __ballot(e != -1);
            if (lane == 0) maskbuf[a_i] = (bal != 0ull) ? 1.0f : 0.0f;
        }
        __syncthreads();

        // ---------------- compute: 4 atoms x 1 column per thread ----------------
        float d0 = bv, d1 = bv, d2 = bv, d3 = bv;
        #pragma unroll
        for (int f = 0; f < NF; ++f) {
            float4 xv = xbuf4[f];            // uniform address -> LDS broadcast
            d0 = fmaf(xv.x, w[f], d0);
            d1 = fmaf(xv.y, w[f], d1);
            d2 = fmaf(xv.z, w[f], d2);
            d3 = fmaf(xv.w, w[f], d3);
        }
        acc += fmaxf(d0, 0.0f) * maskbuf[0];
        acc += fmaxf(d1, 0.0f) * maskbuf[1];
        acc += fmaxf(d2, 0.0f) * maskbuf[2];
        acc += fmaxf(d3, 0.0f) * maskbuf[3];
        __syncthreads();   // before next iteration overwrites xbuf
    }

    out[(size_t)b * NFP + o] = acc;
}

extern "C" void kernel_launch(void* const* d_in, const int* in_sizes, int n_in,
                              void* d_out, int out_size, void* d_ws, size_t ws_size,
                              hipStream_t stream) {
    const float* atoms = (const float*)d_in[0];
    const float* bonds = (const float*)d_in[1];
    const int*   edges = (const int*)d_in[2];
    const float* W     = (const float*)d_in[3];
    const float* bias  = (const float*)d_in[4];
    float* out = (float*)d_out;

    ngf_fp32_kernel<<<NB, 256, 0, stream>>>(atoms, bonds, edges, W, bias, out);
}

// Round 2
// 102.578 us; speedup vs baseline: 4.1482x; 4.1482x over previous
//
#include <hip/hip_runtime.h>

// NeuralGraphOutput: out[b,o] = sum_a mask[b,a] * relu( sum_f x[b,a,f] * W[f,o] + bias[o] )
//   x[b,a,:] = concat(atoms[b,a,0:64], sum_d bonds[b,a,d,0:16])   (80 features)
//   mask[b,a] = any(edges[b,a,d] != -1)
// B=2048, A=256, D=8, FA=64, FB=16, FP=256
// Strategy: 1 block = 1 molecule. Stage X[256][96] bf16 in LDS, W fragments in
// VGPRs, mfma_f32_16x16x32_bf16 over 16-atom strips, accumulate column sums in
// registers (relu is the only reason we touch the 256x256 intermediate at all).

#define NB 2048
#define NA 256
#define ND 8
#define NFA 64
#define NFB 16
#define NF 80
#define NFP 256
#define PITCH 96     // LDS row pitch in bf16 elems (K padded 80 -> 96)

typedef __attribute__((ext_vector_type(8))) short short8;   // 8 bf16 = 4 VGPR
typedef __attribute__((ext_vector_type(4))) float f32x4;    // MFMA C/D

static __device__ __forceinline__ unsigned short f2bf(float f) {
    // round-to-nearest-even fp32 -> bf16
    unsigned int u = __float_as_uint(f);
    return (unsigned short)((u + 0x7FFFu + ((u >> 16) & 1u)) >> 16);
}

__launch_bounds__(256, 3)
__global__ void ngf_mfma_kernel(const float4* __restrict__ atoms4,
                                const float4* __restrict__ bonds4,
                                const int4*   __restrict__ edges4,
                                const float*  __restrict__ W,
                                const float*  __restrict__ bias,
                                float* __restrict__ out)
{
    const int b    = blockIdx.x;
    const int tid  = threadIdx.x;
    const int wave = tid >> 6;
    const int lane = tid & 63;
    const int lrow = lane & 15;    // fragment row (A) / col (B, C/D)
    const int lgrp = lane >> 4;    // k-group (A/B) / row-group (C/D)

    __shared__ unsigned short X[NA * PITCH];   // 48 KB bf16 features
    __shared__ float maskf[NA];                // 1 KB

    const size_t molAtom = (size_t)b * NA;

    // ---------- W as B-fragments in VGPRs (W is 80KB, L2-resident) ----------
    // B frag layout: col = lane&15, k = ks*32 + (lane>>4)*8 + j ; k>=80 -> 0
    short8 bf[3][4];
    float  bia[4];
    #pragma unroll
    for (int nt = 0; nt < 4; ++nt) {
        const int c = (wave * 4 + nt) * 16 + lrow;
        bia[nt] = bias[c];
        #pragma unroll
        for (int ks = 0; ks < 3; ++ks) {
            short8 v;
            #pragma unroll
            for (int j = 0; j < 8; ++j) {
                const int k = ks * 32 + lgrp * 8 + j;
                float w = (k < NF) ? W[k * NFP + c] : 0.0f;
                v[j] = (short)f2bf(w);
            }
            bf[ks][nt] = v;
        }
    }

    // ---------- stage X into LDS ----------
    // atoms part: 4096 float4, coalesced
    #pragma unroll 4
    for (int it = 0; it < 16; ++it) {
        const int flat = it * 256 + tid;
        const int a = flat >> 4, k4 = flat & 15;
        float4 v = atoms4[(molAtom + a) * 16 + k4];
        ushort4 o;
        o.x = f2bf(v.x); o.y = f2bf(v.y); o.z = f2bf(v.z); o.w = f2bf(v.w);
        *(ushort4*)&X[a * PITCH + k4 * 4] = o;
    }
    // bonds part: sum over D=8; 4 threads per atom, float4 streams
    #pragma unroll
    for (int p = 0; p < 4; ++p) {
        const int a = p * 64 + (tid >> 2);
        const int q = tid & 3;                       // quarter of the 16-fb row
        const float4* bp = bonds4 + (molAtom + a) * 32 + q;  // row = 32 float4
        float4 s = {0.0f, 0.0f, 0.0f, 0.0f};
        #pragma unroll
        for (int d = 0; d < 8; ++d) {
            float4 v = bp[d * 4];
            s.x += v.x; s.y += v.y; s.z += v.z; s.w += v.w;
        }
        ushort4 o;
        o.x = f2bf(s.x); o.y = f2bf(s.y); o.z = f2bf(s.z); o.w = f2bf(s.w);
        *(ushort4*)&X[a * PITCH + NFA + q * 4] = o;
    }
    // edges -> mask; zero the K pad (k=80..95)
    {
        const int a = tid;
        int4 e0 = edges4[(molAtom + a) * 2];
        int4 e1 = edges4[(molAtom + a) * 2 + 1];
        bool any = (e0.x != -1) | (e0.y != -1) | (e0.z != -1) | (e0.w != -1)
                 | (e1.x != -1) | (e1.y != -1) | (e1.z != -1) | (e1.w != -1);
        maskf[a] = any ? 1.0f : 0.0f;
        uint4 z = {0u, 0u, 0u, 0u};
        *(uint4*)&X[a * PITCH + 80] = z;   // 8 bf16
        *(uint4*)&X[a * PITCH + 88] = z;   // 8 bf16
    }
    __syncthreads();

    // ---------- compute: 16 strips of 16 atoms; wave owns 64 output cols ----------
    float colsum[4] = {0.0f, 0.0f, 0.0f, 0.0f};
    for (int s = 0; s < 16; ++s) {
        const int row = s * 16 + lrow;                     // A row = lane&15
        const unsigned short* xr = &X[row * PITCH + lgrp * 8];
        short8 a0 = *(const short8*)(xr);                  // k  0..31 slice
        short8 a1 = *(const short8*)(xr + 32);             // k 32..63 slice
        short8 a2 = *(const short8*)(xr + 64);             // k 64..95 slice
        // D rows owned by this lane: atoms s*16 + lgrp*4 + (0..3)
        float4 m4 = *(const float4*)&maskf[s * 16 + lgrp * 4];
        #pragma unroll
        for (int nt = 0; nt < 4; ++nt) {
            f32x4 acc = {0.0f, 0.0f, 0.0f, 0.0f};
            acc = __builtin_amdgcn_mfma_f32_16x16x32_bf16(a0, bf[0][nt], acc, 0, 0, 0);
            acc = __builtin_amdgcn_mfma_f32_16x16x32_bf16(a1, bf[1][nt], acc, 0, 0, 0);
            acc = __builtin_amdgcn_mfma_f32_16x16x32_bf16(a2, bf[2][nt], acc, 0, 0, 0);
            const float bv = bia[nt];
            colsum[nt] += fmaxf(acc[0] + bv, 0.0f) * m4.x
                        + fmaxf(acc[1] + bv, 0.0f) * m4.y
                        + fmaxf(acc[2] + bv, 0.0f) * m4.z
                        + fmaxf(acc[3] + bv, 0.0f) * m4.w;
        }
    }

    // ---------- reduce over the 4 row-groups and store ----------
    #pragma unroll
    for (int nt = 0; nt < 4; ++nt) {
        float v = colsum[nt];
        v += __shfl_xor(v, 16, 64);
        v += __shfl_xor(v, 32, 64);
        if (lane < 16)
            out[(size_t)b * NFP + (wave * 4 + nt) * 16 + lane] = v;
    }
}

extern "C" void kernel_launch(void* const* d_in, const int* in_sizes, int n_in,
                              void* d_out, int out_size, void* d_ws, size_t ws_size,
                              hipStream_t stream) {
    const float4* atoms4 = (const float4*)d_in[0];
    const float4* bonds4 = (const float4*)d_in[1];
    const int4*   edges4 = (const int4*)d_in[2];
    const float*  W      = (const float*)d_in[3];
    const float*  bias   = (const float*)d_in[4];
    float* out = (float*)d_out;

    ngf_mfma_kernel<<<NB, 256, 0, stream>>>(atoms4, bonds4, edges4, W, bias, out);
}